// Round 9
// baseline (199.815 us; speedup 1.0000x reference)
//
#include <hip/hip_runtime.h>

#define HF 240      // fine height/width
#define HC 60       // coarse height/width
#define STRIDEF 4   // HF/HC
#define PADW 2      // WINDOW//2
#define WIN 5
#define CC 256      // C_COARSE
#define CF 128      // C_FINE
#define NPOS 25     // WIN*WIN
#define NPX (HF*HF) // 57600 pixels per image
#define MPB 32      // matches per block in k_coarse
#define TPX 128     // px per k_tgemm block tile

typedef __bf16 bf16x8 __attribute__((ext_vector_type(8)));
typedef __bf16 bf16x4 __attribute__((ext_vector_type(4)));
typedef float  f32x4  __attribute__((ext_vector_type(4)));

// ---------------------------------------------------------------------------
// K1: grid=128 (j), block=256 (k).
//   Wm1h[j][k<128] = bf16(W_merge[j][k])
//   W_effT[k][j]   = sum_q Wm2[j][q] * W_dp[q][k]
//   b_eff[j]       = Wm2[j]·b_dp + b_merge[j]
// ---------------------------------------------------------------------------
__global__ void k_prep(const float* __restrict__ W_dp, const float* __restrict__ b_dp,
                       const float* __restrict__ W_merge, const float* __restrict__ b_merge,
                       __bf16* __restrict__ Wm1h, float* __restrict__ W_effT,
                       float* __restrict__ b_eff) {
    const int j = blockIdx.x;    // 0..127 output channel
    const int k = threadIdx.x;   // 0..255 coarse dim
    const float* wm2 = W_merge + (size_t)j * (2 * CF) + CF;

    float acc = 0.f, accb = 0.f;
    for (int q = 0; q < CF; ++q) {
        const float wq = wm2[q];                    // wave-uniform
        acc  += wq * W_dp[(size_t)q * CC + k];      // coalesced
        accb += wq * b_dp[q];
    }
    W_effT[(size_t)k * CF + j] = acc;

    if (k < CF)
        Wm1h[(size_t)j * CF + k] = (__bf16)W_merge[(size_t)j * (2 * CF) + k];
    if (k == 0)
        b_eff[j] = accb + b_merge[j];
}

// ---------------------------------------------------------------------------
// K2: c_all[m][j] = b_eff[j] + sum_k W_eff[j][k] * coarse_vec(m)[k]
// 32 matches/block: W_effT (128KB) streamed once per 32 matches.
// ---------------------------------------------------------------------------
__global__ void k_coarse(const float* __restrict__ c1, const float* __restrict__ c2,
                         const int* __restrict__ bidx, const int* __restrict__ ridx,
                         const int* __restrict__ cidx, int M,
                         const float* __restrict__ W_effT, const float* __restrict__ b_eff,
                         float* __restrict__ c_all) {
    const int m0 = blockIdx.x * MPB;
    const int j  = threadIdx.x;  // 0..127
    const int twoM = 2 * M;
    __shared__ float v[MPB * CC];   // 32 KB

    const int nm = (twoM - m0) < MPB ? (twoM - m0) : MPB;
    for (int mm = 0; mm < nm; ++mm) {
        int m = m0 + mm;
        const float* src;
        if (m < M) src = c1 + ((size_t)bidx[m] * (HC * HC) + ridx[m]) * CC;
        else       src = c2 + ((size_t)bidx[m - M] * (HC * HC) + cidx[m - M]) * CC;
        v[mm * CC + j]      = src[j];
        v[mm * CC + j + CF] = src[j + CF];
    }
    __syncthreads();

    float acc[MPB];
    const float be = b_eff[j];
    #pragma unroll
    for (int mm = 0; mm < MPB; ++mm) acc[mm] = be;

    for (int k = 0; k < CC; k += 4) {
        float w0 = W_effT[(k + 0) * CF + j];
        float w1 = W_effT[(k + 1) * CF + j];
        float w2 = W_effT[(k + 2) * CF + j];
        float w3 = W_effT[(k + 3) * CF + j];
        #pragma unroll
        for (int mm = 0; mm < MPB; ++mm) {
            const f32x4 vv = *(const f32x4*)&v[mm * CC + k];
            acc[mm] += w0 * vv.x + w1 * vv.y + w2 * vv.z + w3 * vv.w;
        }
    }
    for (int mm = 0; mm < nm; ++mm)
        c_all[(size_t)(m0 + mm) * CF + j] = acc[mm];
}

// ---------------------------------------------------------------------------
// KTG v5 (unchanged from R8): m97-structure transpose+GEMM, global_load_lds.
// Block (256 thr, 4 waves) = 128 px x 128 ch; 4 K-chunks of 32 ch,
// double-buffered fp32 LDS [32ch][128px] (2 x 16 KB).
// grid = (450, 4), block = 256.
// ---------------------------------------------------------------------------
__global__ __launch_bounds__(256, 4) void k_tgemm(
    const float* __restrict__ f1, const float* __restrict__ f2,
    const __bf16* __restrict__ Wm1h, __bf16* __restrict__ V) {

    const int slot = blockIdx.y;
    const float* src = (slot >= 2 ? f2 : f1) + (size_t)(slot & 1) * CF * NPX;
    const int px0 = blockIdx.x * TPX;
    const int t  = threadIdx.x;
    const int l  = t & 63;
    const int w  = t >> 6;           // wave 0..3, owns j = w*32..+31
    const int lo16 = l & 15;
    const int hi   = l >> 4;

    __shared__ __attribute__((aligned(16))) float chkf[2][32 * TPX]; // 2 x 16 KB

    const int seg = l >> 5;          // 0/1: which ch row within an instr
    const int q4  = (l & 31) * 4;    // LDS px' quad base

#define STAGE(c, b)                                                           \
    {                                                                         \
        _Pragma("unroll")                                                     \
        for (int ii = 0; ii < 4; ++ii) {                                      \
            const int i   = w * 4 + ii;                                       \
            const int chl = 2 * i + seg;                                      \
            const int ch  = (c) * 32 + chl;                                   \
            const int pxg = q4 ^ (((ch >> 3) & 3) << 4);                      \
            const float* gp = src + (size_t)ch * NPX + px0 + pxg;             \
            __builtin_amdgcn_global_load_lds(                                 \
                (const __attribute__((address_space(1))) void*)gp,            \
                (__attribute__((address_space(3))) void*)&chkf[b][i * 256],   \
                16, 0, 0);                                                    \
        }                                                                     \
    }

    f32x4 acc[8][2];
    #pragma unroll
    for (int mt = 0; mt < 8; ++mt) {
        acc[mt][0] = (f32x4){0.f, 0.f, 0.f, 0.f};
        acc[mt][1] = (f32x4){0.f, 0.f, 0.f, 0.f};
    }

    STAGE(0, 0);

    #pragma unroll
    for (int c = 0; c < 4; ++c) {
        const int b = c & 1;
        if (c < 3) STAGE(c + 1, b ^ 1);
        __syncthreads();

        const bf16x8 bf0 = *reinterpret_cast<const bf16x8*>(
            Wm1h + (size_t)(w * 32 + 2 * lo16 + 0) * CF + c * 32 + hi * 8);
        const bf16x8 bf1 = *reinterpret_cast<const bf16x8*>(
            Wm1h + (size_t)(w * 32 + 2 * lo16 + 1) * CF + c * 32 + hi * 8);

        #pragma unroll
        for (int mt = 0; mt < 8; ++mt) {
            const int pxr = (mt * 16 + lo16) ^ (hi << 4);   // swizzled read col
            bf16x8 a;
            #pragma unroll
            for (int e = 0; e < 8; ++e)
                a[e] = (__bf16)chkf[b][(hi * 8 + e) * TPX + pxr];
            acc[mt][0] = __builtin_amdgcn_mfma_f32_16x16x32_bf16(a, bf0, acc[mt][0], 0, 0, 0);
            acc[mt][1] = __builtin_amdgcn_mfma_f32_16x16x32_bf16(a, bf1, acc[mt][1], 0, 0, 0);
        }
        __syncthreads();
    }
#undef STAGE

    // epilogue: V[px][j], dword = (j_even, j_odd) bf16x2
    uint* Vp = (uint*)(V + ((size_t)slot * NPX + px0) * CF);
    const int dcol = w * 16 + lo16;
    #pragma unroll
    for (int mt = 0; mt < 8; ++mt) {
        #pragma unroll
        for (int reg = 0; reg < 4; ++reg) {
            const int px = mt * 16 + hi * 4 + reg;
            union { uint u; __bf16 h[2]; } cv;
            cv.h[0] = (__bf16)acc[mt][0][reg];
            cv.h[1] = (__bf16)acc[mt][1][reg];
            Vp[(size_t)px * 64 + dcol] = cv.u;
        }
    }
}

// ---------------------------------------------------------------------------
// K4: gather-add stream with NON-TEMPORAL out stores (protect L3 residency
// of {input, V, c_all}: out is 77MB write-once-never-read).
// grid = 2M, block = 256. No LDS, no sync.
// ---------------------------------------------------------------------------
__global__ __launch_bounds__(256) void k_gather(
    const __bf16* __restrict__ V,
    const int* __restrict__ bidx, const int* __restrict__ ridx,
    const int* __restrict__ cidx, int M,
    const float* __restrict__ c_all, float* __restrict__ out) {

    const int m = blockIdx.x;
    const int t = threadIdx.x;
    const int g  = t >> 5;    // row group 0..7
    const int l32 = t & 31;   // covers 128 ch as 32 float4

    int b, lin, ii;
    if (m < M) { ii = 0; b = bidx[m];     lin = ridx[m]; }
    else       { ii = 1; b = bidx[m - M]; lin = cidx[m - M]; }
    const int slot = ii * 2 + b;
    const int r  = lin / HC, c = lin - r * HC;
    const int y0 = r * STRIDEF - PADW;
    const int x0 = c * STRIDEF - PADW;

    const f32x4 c4 = *reinterpret_cast<const f32x4*>(c_all + (size_t)m * CF + l32 * 4);
    const __bf16* Vb = V + (size_t)slot * NPX * CF;
    float* ob = out + (size_t)m * (NPOS * CF) + l32 * 4;

    #pragma unroll
    for (int pass = 0; pass < 4; ++pass) {
        const int p = pass * 8 + g;
        if (p < NPOS) {
            const int wy = (p * 13) >> 6;      // p/5 for p<32
            const int wx = p - wy * WIN;
            const int y = y0 + wy, x = x0 + wx;
            f32x4 o = c4;
            if (y >= 0 && x >= 0) {
                const bf16x4 v = *reinterpret_cast<const bf16x4*>(Vb + (size_t)(y * HF + x) * CF + l32 * 4);
                o.x += (float)v.x; o.y += (float)v.y; o.z += (float)v.z; o.w += (float)v.w;
            }
            __builtin_nontemporal_store(o, reinterpret_cast<f32x4*>(ob + (size_t)p * CF));
        }
    }
}

// ---------------------------------------------------------------------------
// Fallback main (R2 path): gather directly from fp32 NCHW images.
// ---------------------------------------------------------------------------
__global__ __launch_bounds__(256) void k_main_direct(
    const float* __restrict__ f1, const float* __restrict__ f2,
    const int* __restrict__ bidx, const int* __restrict__ ridx,
    const int* __restrict__ cidx, int M,
    const __bf16* __restrict__ Wm1h, const float* __restrict__ c_all,
    float* __restrict__ out) {

    const int m = blockIdx.x;
    const int t = threadIdx.x;
    const int l    = t & 63;
    const int wv   = t >> 6;
    const int lo16 = l & 15;
    const int hi   = l >> 4;

    __shared__ __bf16 patch[32 * CF];

    bf16x8 bfrag[2][4];
    #pragma unroll
    for (int nt2 = 0; nt2 < 2; ++nt2) {
        const int j = wv * 32 + nt2 * 16 + lo16;
        #pragma unroll
        for (int kt = 0; kt < 4; ++kt)
            bfrag[nt2][kt] = *reinterpret_cast<const bf16x8*>(Wm1h + (size_t)j * CF + kt * 32 + hi * 8);
    }

    const float* img; int b, lin;
    if (m < M) { img = f1; b = bidx[m];     lin = ridx[m]; }
    else       { img = f2; b = bidx[m - M]; lin = cidx[m - M]; }
    const int r  = lin / HC, c = lin - r * HC;
    const int y0 = r * STRIDEF - PADW;
    const int x0 = c * STRIDEF - PADW;

    for (int task = t; task < CF * WIN; task += 256) {
        const int ch = task / WIN;
        const int wy = task - ch * WIN;
        const int y  = y0 + wy;
        const bool yok = (y >= 0);
        const float* rowp = img + (((size_t)b * CF + ch) * HF + (yok ? y : 0)) * HF;
        #pragma unroll
        for (int wx = 0; wx < WIN; ++wx) {
            const int x = x0 + wx;
            const float val = (yok && x >= 0) ? rowp[x] : 0.f;
            const int pos = wy * WIN + wx;
            patch[pos * CF + (ch ^ ((pos & 7) << 3))] = (__bf16)val;
        }
    }
    __syncthreads();

    f32x4 acc[2][2];
    #pragma unroll
    for (int mt = 0; mt < 2; ++mt)
        #pragma unroll
        for (int nt2 = 0; nt2 < 2; ++nt2)
            acc[mt][nt2] = (f32x4){0.f, 0.f, 0.f, 0.f};

    const int swz = (lo16 & 7) << 3;
    #pragma unroll
    for (int kt = 0; kt < 4; ++kt) {
        const int koff = (kt * 32 + hi * 8) ^ swz;
        bf16x8 a0 = *reinterpret_cast<const bf16x8*>(&patch[ lo16       * CF + koff]);
        bf16x8 a1 = *reinterpret_cast<const bf16x8*>(&patch[(16 + lo16) * CF + koff]);
        #pragma unroll
        for (int nt2 = 0; nt2 < 2; ++nt2) {
            acc[0][nt2] = __builtin_amdgcn_mfma_f32_16x16x32_bf16(a0, bfrag[nt2][kt], acc[0][nt2], 0, 0, 0);
            acc[1][nt2] = __builtin_amdgcn_mfma_f32_16x16x32_bf16(a1, bfrag[nt2][kt], acc[1][nt2], 0, 0, 0);
        }
    }

    float* ob = out + (size_t)m * (NPOS * CF);
    #pragma unroll
    for (int nt2 = 0; nt2 < 2; ++nt2) {
        const int j  = wv * 32 + nt2 * 16 + lo16;
        const float cv = c_all[(size_t)m * CF + j];
        #pragma unroll
        for (int mt = 0; mt < 2; ++mt) {
            #pragma unroll
            for (int reg = 0; reg < 4; ++reg) {
                const int p = mt * 16 + hi * 4 + reg;
                if (p < NPOS)
                    ob[(size_t)p * CF + j] = acc[mt][nt2][reg] + cv;
            }
        }
    }
}

// ---------------------------------------------------------------------------
extern "C" void kernel_launch(void* const* d_in, const int* in_sizes, int n_in,
                              void* d_out, int out_size, void* d_ws, size_t ws_size,
                              hipStream_t stream) {
    const float* c1      = (const float*)d_in[0];
    const float* c2      = (const float*)d_in[1];
    const float* f1      = (const float*)d_in[2];
    const float* f2      = (const float*)d_in[3];
    const int*   bidx    = (const int*)d_in[4];
    const int*   ridx    = (const int*)d_in[5];
    const int*   cidx    = (const int*)d_in[6];
    const float* W_dp    = (const float*)d_in[9];
    const float* b_dp    = (const float*)d_in[10];
    const float* W_merge = (const float*)d_in[11];
    const float* b_merge = (const float*)d_in[12];
    const int M = in_sizes[4];

    char* ws = (char*)d_ws;
    __bf16* Wm1h  = (__bf16*)(ws);                //  32 KB
    float* W_effT = (float*)(ws + (64 << 10));    // 128 KB
    float* b_eff  = (float*)(ws + (192 << 10));   // 512 B
    float* c_all  = (float*)(ws + (256 << 10));   // 2M*128*4 ~ 3.07 MB
    __bf16* V     = (__bf16*)(ws + (4 << 20));    // 4*57600*128*2 = 58.98 MB

    const size_t need_V = (size_t)(4 << 20) + (size_t)4 * NPX * CF * 2;

    hipLaunchKernelGGL(k_prep, dim3(CF), dim3(CC), 0, stream,
                       W_dp, b_dp, W_merge, b_merge, Wm1h, W_effT, b_eff);
    hipLaunchKernelGGL(k_coarse, dim3((2 * M + MPB - 1) / MPB), dim3(CF), 0, stream,
                       c1, c2, bidx, ridx, cidx, M, W_effT, b_eff, c_all);

    if (ws_size >= need_V) {
        hipLaunchKernelGGL(k_tgemm, dim3(NPX / TPX, 4), dim3(256), 0, stream,
                           f1, f2, Wm1h, V);
        hipLaunchKernelGGL(k_gather, dim3(2 * M), dim3(256), 0, stream,
                           V, bidx, ridx, cidx, M, c_all, (float*)d_out);
    } else {
        hipLaunchKernelGGL(k_main_direct, dim3(2 * M), dim3(256), 0, stream,
                           f1, f2, bidx, ridx, cidx, M, Wm1h, c_all, (float*)d_out);
    }
}

// Round 10
// 92.948 us; speedup vs baseline: 2.1497x; 2.1497x over previous
//
#include <hip/hip_runtime.h>

#define HF 240      // fine height/width
#define HC 60       // coarse height/width
#define STRIDEF 4   // HF/HC
#define PADW 2      // WINDOW//2
#define WIN 5
#define CC 256      // C_COARSE
#define CF 128      // C_FINE
#define NPOS 25     // WIN*WIN
#define NPX (HF*HF) // 57600 pixels per image
#define MPB 16      // matches per block in k_coarse (16: 375 blocks, ~8us; 32 regressed to 147us — grid too small, R9)
#define TPX 128     // px per k_tgemm block tile

typedef __bf16 bf16x8 __attribute__((ext_vector_type(8)));
typedef __bf16 bf16x4 __attribute__((ext_vector_type(4)));
typedef float  f32x4  __attribute__((ext_vector_type(4)));

// ---------------------------------------------------------------------------
// K1: grid=128 (j), block=256 (k).
//   Wm1h[j][k<128] = bf16(W_merge[j][k])
//   W_effT[k][j]   = sum_q Wm2[j][q] * W_dp[q][k]
//   b_eff[j]       = Wm2[j]·b_dp + b_merge[j]
// ---------------------------------------------------------------------------
__global__ void k_prep(const float* __restrict__ W_dp, const float* __restrict__ b_dp,
                       const float* __restrict__ W_merge, const float* __restrict__ b_merge,
                       __bf16* __restrict__ Wm1h, float* __restrict__ W_effT,
                       float* __restrict__ b_eff) {
    const int j = blockIdx.x;    // 0..127 output channel
    const int k = threadIdx.x;   // 0..255 coarse dim
    const float* wm2 = W_merge + (size_t)j * (2 * CF) + CF;

    float acc = 0.f, accb = 0.f;
    for (int q = 0; q < CF; ++q) {
        const float wq = wm2[q];                    // wave-uniform
        acc  += wq * W_dp[(size_t)q * CC + k];      // coalesced
        accb += wq * b_dp[q];
    }
    W_effT[(size_t)k * CF + j] = acc;

    if (k < CF)
        Wm1h[(size_t)j * CF + k] = (__bf16)W_merge[(size_t)j * (2 * CF) + k];
    if (k == 0)
        b_eff[j] = accb + b_merge[j];
}

// ---------------------------------------------------------------------------
// K2: c_all[m][j] = b_eff[j] + sum_k W_eff[j][k] * coarse_vec(m)[k]
// 16 matches/block -> 375 blocks (>1/CU). MPB=32 (188 blocks) regressed 18x.
// ---------------------------------------------------------------------------
__global__ void k_coarse(const float* __restrict__ c1, const float* __restrict__ c2,
                         const int* __restrict__ bidx, const int* __restrict__ ridx,
                         const int* __restrict__ cidx, int M,
                         const float* __restrict__ W_effT, const float* __restrict__ b_eff,
                         float* __restrict__ c_all) {
    const int m0 = blockIdx.x * MPB;
    const int j  = threadIdx.x;  // 0..127
    const int twoM = 2 * M;
    __shared__ float v[MPB * CC];   // 16 KB

    const int nm = (twoM - m0) < MPB ? (twoM - m0) : MPB;
    for (int mm = 0; mm < nm; ++mm) {
        int m = m0 + mm;
        const float* src;
        if (m < M) src = c1 + ((size_t)bidx[m] * (HC * HC) + ridx[m]) * CC;
        else       src = c2 + ((size_t)bidx[m - M] * (HC * HC) + cidx[m - M]) * CC;
        v[mm * CC + j]      = src[j];
        v[mm * CC + j + CF] = src[j + CF];
    }
    __syncthreads();

    float acc[MPB];
    const float be = b_eff[j];
    #pragma unroll
    for (int mm = 0; mm < MPB; ++mm) acc[mm] = be;

    for (int k = 0; k < CC; k += 4) {
        float w0 = W_effT[(k + 0) * CF + j];
        float w1 = W_effT[(k + 1) * CF + j];
        float w2 = W_effT[(k + 2) * CF + j];
        float w3 = W_effT[(k + 3) * CF + j];
        #pragma unroll
        for (int mm = 0; mm < MPB; ++mm) {
            const f32x4 vv = *(const f32x4*)&v[mm * CC + k];
            acc[mm] += w0 * vv.x + w1 * vv.y + w2 * vv.z + w3 * vv.w;
        }
    }
    for (int mm = 0; mm < nm; ++mm)
        c_all[(size_t)(m0 + mm) * CF + j] = acc[mm];
}

// ---------------------------------------------------------------------------
// KTG v5 (unchanged from R8): m97-structure transpose+GEMM, global_load_lds.
// Block (256 thr, 4 waves) = 128 px x 128 ch; 4 K-chunks of 32 ch,
// double-buffered fp32 LDS [32ch][128px] (2 x 16 KB).
// grid = (450, 4), block = 256.
// ---------------------------------------------------------------------------
__global__ __launch_bounds__(256, 4) void k_tgemm(
    const float* __restrict__ f1, const float* __restrict__ f2,
    const __bf16* __restrict__ Wm1h, __bf16* __restrict__ V) {

    const int slot = blockIdx.y;
    const float* src = (slot >= 2 ? f2 : f1) + (size_t)(slot & 1) * CF * NPX;
    const int px0 = blockIdx.x * TPX;
    const int t  = threadIdx.x;
    const int l  = t & 63;
    const int w  = t >> 6;           // wave 0..3, owns j = w*32..+31
    const int lo16 = l & 15;
    const int hi   = l >> 4;

    __shared__ __attribute__((aligned(16))) float chkf[2][32 * TPX]; // 2 x 16 KB

    const int seg = l >> 5;          // 0/1: which ch row within an instr
    const int q4  = (l & 31) * 4;    // LDS px' quad base

#define STAGE(c, b)                                                           \
    {                                                                         \
        _Pragma("unroll")                                                     \
        for (int ii = 0; ii < 4; ++ii) {                                      \
            const int i   = w * 4 + ii;                                       \
            const int chl = 2 * i + seg;                                      \
            const int ch  = (c) * 32 + chl;                                   \
            const int pxg = q4 ^ (((ch >> 3) & 3) << 4);                      \
            const float* gp = src + (size_t)ch * NPX + px0 + pxg;             \
            __builtin_amdgcn_global_load_lds(                                 \
                (const __attribute__((address_space(1))) void*)gp,            \
                (__attribute__((address_space(3))) void*)&chkf[b][i * 256],   \
                16, 0, 0);                                                    \
        }                                                                     \
    }

    f32x4 acc[8][2];
    #pragma unroll
    for (int mt = 0; mt < 8; ++mt) {
        acc[mt][0] = (f32x4){0.f, 0.f, 0.f, 0.f};
        acc[mt][1] = (f32x4){0.f, 0.f, 0.f, 0.f};
    }

    STAGE(0, 0);

    #pragma unroll
    for (int c = 0; c < 4; ++c) {
        const int b = c & 1;
        if (c < 3) STAGE(c + 1, b ^ 1);
        __syncthreads();

        const bf16x8 bf0 = *reinterpret_cast<const bf16x8*>(
            Wm1h + (size_t)(w * 32 + 2 * lo16 + 0) * CF + c * 32 + hi * 8);
        const bf16x8 bf1 = *reinterpret_cast<const bf16x8*>(
            Wm1h + (size_t)(w * 32 + 2 * lo16 + 1) * CF + c * 32 + hi * 8);

        #pragma unroll
        for (int mt = 0; mt < 8; ++mt) {
            const int pxr = (mt * 16 + lo16) ^ (hi << 4);   // swizzled read col
            bf16x8 a;
            #pragma unroll
            for (int e = 0; e < 8; ++e)
                a[e] = (__bf16)chkf[b][(hi * 8 + e) * TPX + pxr];
            acc[mt][0] = __builtin_amdgcn_mfma_f32_16x16x32_bf16(a, bf0, acc[mt][0], 0, 0, 0);
            acc[mt][1] = __builtin_amdgcn_mfma_f32_16x16x32_bf16(a, bf1, acc[mt][1], 0, 0, 0);
        }
        __syncthreads();
    }
#undef STAGE

    // epilogue: V[px][j], dword = (j_even, j_odd) bf16x2
    uint* Vp = (uint*)(V + ((size_t)slot * NPX + px0) * CF);
    const int dcol = w * 16 + lo16;
    #pragma unroll
    for (int mt = 0; mt < 8; ++mt) {
        #pragma unroll
        for (int reg = 0; reg < 4; ++reg) {
            const int px = mt * 16 + hi * 4 + reg;
            union { uint u; __bf16 h[2]; } cv;
            cv.h[0] = (__bf16)acc[mt][0][reg];
            cv.h[1] = (__bf16)acc[mt][1][reg];
            Vp[(size_t)px * 64 + dcol] = cv.u;
        }
    }
}

// ---------------------------------------------------------------------------
// K4: gather-add stream with NON-TEMPORAL out stores (protect L3 residency
// of {input, V, c_all}: out is 77MB write-once-never-read).
// grid = 2M, block = 256. No LDS, no sync.
// ---------------------------------------------------------------------------
__global__ __launch_bounds__(256) void k_gather(
    const __bf16* __restrict__ V,
    const int* __restrict__ bidx, const int* __restrict__ ridx,
    const int* __restrict__ cidx, int M,
    const float* __restrict__ c_all, float* __restrict__ out) {

    const int m = blockIdx.x;
    const int t = threadIdx.x;
    const int g  = t >> 5;    // row group 0..7
    const int l32 = t & 31;   // covers 128 ch as 32 float4

    int b, lin, ii;
    if (m < M) { ii = 0; b = bidx[m];     lin = ridx[m]; }
    else       { ii = 1; b = bidx[m - M]; lin = cidx[m - M]; }
    const int slot = ii * 2 + b;
    const int r  = lin / HC, c = lin - r * HC;
    const int y0 = r * STRIDEF - PADW;
    const int x0 = c * STRIDEF - PADW;

    const f32x4 c4 = *reinterpret_cast<const f32x4*>(c_all + (size_t)m * CF + l32 * 4);
    const __bf16* Vb = V + (size_t)slot * NPX * CF;
    float* ob = out + (size_t)m * (NPOS * CF) + l32 * 4;

    #pragma unroll
    for (int pass = 0; pass < 4; ++pass) {
        const int p = pass * 8 + g;
        if (p < NPOS) {
            const int wy = (p * 13) >> 6;      // p/5 for p<32
            const int wx = p - wy * WIN;
            const int y = y0 + wy, x = x0 + wx;
            f32x4 o = c4;
            if (y >= 0 && x >= 0) {
                const bf16x4 v = *reinterpret_cast<const bf16x4*>(Vb + (size_t)(y * HF + x) * CF + l32 * 4);
                o.x += (float)v.x; o.y += (float)v.y; o.z += (float)v.z; o.w += (float)v.w;
            }
            __builtin_nontemporal_store(o, reinterpret_cast<f32x4*>(ob + (size_t)p * CF));
        }
    }
}

// ---------------------------------------------------------------------------
// Fallback main (R2 path): gather directly from fp32 NCHW images.
// ---------------------------------------------------------------------------
__global__ __launch_bounds__(256) void k_main_direct(
    const float* __restrict__ f1, const float* __restrict__ f2,
    const int* __restrict__ bidx, const int* __restrict__ ridx,
    const int* __restrict__ cidx, int M,
    const __bf16* __restrict__ Wm1h, const float* __restrict__ c_all,
    float* __restrict__ out) {

    const int m = blockIdx.x;
    const int t = threadIdx.x;
    const int l    = t & 63;
    const int wv   = t >> 6;
    const int lo16 = l & 15;
    const int hi   = l >> 4;

    __shared__ __bf16 patch[32 * CF];

    bf16x8 bfrag[2][4];
    #pragma unroll
    for (int nt2 = 0; nt2 < 2; ++nt2) {
        const int j = wv * 32 + nt2 * 16 + lo16;
        #pragma unroll
        for (int kt = 0; kt < 4; ++kt)
            bfrag[nt2][kt] = *reinterpret_cast<const bf16x8*>(Wm1h + (size_t)j * CF + kt * 32 + hi * 8);
    }

    const float* img; int b, lin;
    if (m < M) { img = f1; b = bidx[m];     lin = ridx[m]; }
    else       { img = f2; b = bidx[m - M]; lin = cidx[m - M]; }
    const int r  = lin / HC, c = lin - r * HC;
    const int y0 = r * STRIDEF - PADW;
    const int x0 = c * STRIDEF - PADW;

    for (int task = t; task < CF * WIN; task += 256) {
        const int ch = task / WIN;
        const int wy = task - ch * WIN;
        const int y  = y0 + wy;
        const bool yok = (y >= 0);
        const float* rowp = img + (((size_t)b * CF + ch) * HF + (yok ? y : 0)) * HF;
        #pragma unroll
        for (int wx = 0; wx < WIN; ++wx) {
            const int x = x0 + wx;
            const float val = (yok && x >= 0) ? rowp[x] : 0.f;
            const int pos = wy * WIN + wx;
            patch[pos * CF + (ch ^ ((pos & 7) << 3))] = (__bf16)val;
        }
    }
    __syncthreads();

    f32x4 acc[2][2];
    #pragma unroll
    for (int mt = 0; mt < 2; ++mt)
        #pragma unroll
        for (int nt2 = 0; nt2 < 2; ++nt2)
            acc[mt][nt2] = (f32x4){0.f, 0.f, 0.f, 0.f};

    const int swz = (lo16 & 7) << 3;
    #pragma unroll
    for (int kt = 0; kt < 4; ++kt) {
        const int koff = (kt * 32 + hi * 8) ^ swz;
        bf16x8 a0 = *reinterpret_cast<const bf16x8*>(&patch[ lo16       * CF + koff]);
        bf16x8 a1 = *reinterpret_cast<const bf16x8*>(&patch[(16 + lo16) * CF + koff]);
        #pragma unroll
        for (int nt2 = 0; nt2 < 2; ++nt2) {
            acc[0][nt2] = __builtin_amdgcn_mfma_f32_16x16x32_bf16(a0, bfrag[nt2][kt], acc[0][nt2], 0, 0, 0);
            acc[1][nt2] = __builtin_amdgcn_mfma_f32_16x16x32_bf16(a1, bfrag[nt2][kt], acc[1][nt2], 0, 0, 0);
        }
    }

    float* ob = out + (size_t)m * (NPOS * CF);
    #pragma unroll
    for (int nt2 = 0; nt2 < 2; ++nt2) {
        const int j  = wv * 32 + nt2 * 16 + lo16;
        const float cv = c_all[(size_t)m * CF + j];
        #pragma unroll
        for (int mt = 0; mt < 2; ++mt) {
            #pragma unroll
            for (int reg = 0; reg < 4; ++reg) {
                const int p = mt * 16 + hi * 4 + reg;
                if (p < NPOS)
                    ob[(size_t)p * CF + j] = acc[mt][nt2][reg] + cv;
            }
        }
    }
}

// ---------------------------------------------------------------------------
extern "C" void kernel_launch(void* const* d_in, const int* in_sizes, int n_in,
                              void* d_out, int out_size, void* d_ws, size_t ws_size,
                              hipStream_t stream) {
    const float* c1      = (const float*)d_in[0];
    const float* c2      = (const float*)d_in[1];
    const float* f1      = (const float*)d_in[2];
    const float* f2      = (const float*)d_in[3];
    const int*   bidx    = (const int*)d_in[4];
    const int*   ridx    = (const int*)d_in[5];
    const int*   cidx    = (const int*)d_in[6];
    const float* W_dp    = (const float*)d_in[9];
    const float* b_dp    = (const float*)d_in[10];
    const float* W_merge = (const float*)d_in[11];
    const float* b_merge = (const float*)d_in[12];
    const int M = in_sizes[4];

    char* ws = (char*)d_ws;
    __bf16* Wm1h  = (__bf16*)(ws);                //  32 KB
    float* W_effT = (float*)(ws + (64 << 10));    // 128 KB
    float* b_eff  = (float*)(ws + (192 << 10));   // 512 B
    float* c_all  = (float*)(ws + (256 << 10));   // 2M*128*4 ~ 3.07 MB
    __bf16* V     = (__bf16*)(ws + (4 << 20));    // 4*57600*128*2 = 58.98 MB

    const size_t need_V = (size_t)(4 << 20) + (size_t)4 * NPX * CF * 2;

    hipLaunchKernelGGL(k_prep, dim3(CF), dim3(CC), 0, stream,
                       W_dp, b_dp, W_merge, b_merge, Wm1h, W_effT, b_eff);
    hipLaunchKernelGGL(k_coarse, dim3((2 * M + MPB - 1) / MPB), dim3(CF), 0, stream,
                       c1, c2, bidx, ridx, cidx, M, W_effT, b_eff, c_all);

    if (ws_size >= need_V) {
        hipLaunchKernelGGL(k_tgemm, dim3(NPX / TPX, 4), dim3(256), 0, stream,
                           f1, f2, Wm1h, V);
        hipLaunchKernelGGL(k_gather, dim3(2 * M), dim3(256), 0, stream,
                           V, bidx, ridx, cidx, M, c_all, (float*)d_out);
    } else {
        hipLaunchKernelGGL(k_main_direct, dim3(2 * M), dim3(256), 0, stream,
                           f1, f2, bidx, ridx, cidx, M, Wm1h, c_all, (float*)d_out);
    }
}